// Round 8
// baseline (896.805 us; speedup 1.0000x reference)
//
#include <hip/hip_runtime.h>
#include <hip/hip_bf16.h>

// GCN forward, CSR-gather formulation.
// Gathers are fabric-bound (~3.85 TB/s random-granule ceiling, measured r6).
// GEMMs: W staged in LDS; A via broadcast global loads (vmcnt path, NOT s_load:
//   keeps A waits off lgkmcnt which ds_read uses); explicit A register dbuf.
// r7 lesson: __launch_bounds__ min-waves=4 capped VGPR at 64 and starved the
//   A-load pipeline -> use (256,2) so the allocator can hold cur/nxt in flight.

#define NN 100000
#define NE 1600000
#define NG 512
#define NBLK ((NN + 1023) / 1024)   // 98 scan blocks

// ---------------- CSR build (counting sort by dst) ----------------

__global__ void k_zero_int(int* p, int n) {
    int i = blockIdx.x * blockDim.x + threadIdx.x;
    if (i < n) p[i] = 0;
}

__global__ void k_hist(const int* __restrict__ dst, int* cnt, int e) {
    int i = blockIdx.x * blockDim.x + threadIdx.x;
    if (i < e) atomicAdd(&cnt[dst[i]], 1);
}

// pad x[N,78] -> xp[N,80] (320B rows, 3-line span)
__global__ void k_xpad(const float* __restrict__ x, float* __restrict__ xp) {
    int i = blockIdx.x * blockDim.x + threadIdx.x;   // over NN*80
    if (i >= NN * 80) return;
    int n = i / 80, c = i - n * 80;
    xp[i] = (c < 78) ? x[(size_t)n * 78 + c] : 0.0f;
}

__global__ __launch_bounds__(256) void k_bsum(const int* __restrict__ cnt, int* __restrict__ bsum) {
    __shared__ int s[256];
    int b = blockIdx.x, t = threadIdx.x;
    int base = b * 1024 + t * 4;
    int v = 0;
#pragma unroll
    for (int j = 0; j < 4; j++) { int i = base + j; if (i < NN) v += cnt[i]; }
    s[t] = v; __syncthreads();
    for (int off = 128; off > 0; off >>= 1) {
        if (t < off) s[t] += s[t + off];
        __syncthreads();
    }
    if (t == 0) bsum[b] = s[0];
}

// per-block scan (+ inlined 98-entry bsum scan) -> row_ptr, cursor; also dinv.
__global__ __launch_bounds__(256) void k_scan_blocks(const int* __restrict__ cnt,
    const int* __restrict__ bsum, int* __restrict__ row_ptr, int* __restrict__ cursor,
    float* __restrict__ dinv) {
    __shared__ int s[256];
    __shared__ int sb[128];
    int b = blockIdx.x, t = threadIdx.x;
    if (t < 128) sb[t] = (t < NBLK) ? bsum[t] : 0;
    __syncthreads();
    if (t < 128) {
        for (int off = 1; off < 128; off <<= 1) {
            int u = (t >= off) ? sb[t - off] : 0;
            __syncthreads();
            sb[t] += u;
            __syncthreads();
        }
    } else {
        for (int off = 1; off < 128; off <<= 1) { __syncthreads(); __syncthreads(); }
    }
    __syncthreads();
    int boff = (b == 0) ? 0 : sb[b - 1];

    int base = b * 1024 + t * 4;
    int v[4]; int sum = 0;
#pragma unroll
    for (int j = 0; j < 4; j++) {
        int i = base + j;
        v[j] = (i < NN) ? cnt[i] : 0;
        sum += v[j];
        if (i < NN) dinv[i] = rsqrtf((float)v[j] + 1.0f);
    }
    s[t] = sum; __syncthreads();
    for (int off = 1; off < 256; off <<= 1) {
        int u = (t >= off) ? s[t - off] : 0;
        __syncthreads();
        s[t] += u;
        __syncthreads();
    }
    int excl = s[t] - sum + boff;
#pragma unroll
    for (int j = 0; j < 4; j++) {
        int i = base + j;
        if (i < NN) { row_ptr[i] = excl; cursor[i] = excl; excl += v[j]; }
    }
    if (b == 0 && t == 0) row_ptr[NN] = NE;
}

// counting-sort fill (one packed 8B store per edge) + gmax zero-init
__global__ void k_fillslots(const int* __restrict__ src, const int* __restrict__ dst,
    const float* __restrict__ dinv, int* cursor, int2* __restrict__ es,
    float* __restrict__ gmax, int e) {
    int i = blockIdx.x * blockDim.x + threadIdx.x;
    if (i < NG * 256) gmax[i] = 0.0f;
    if (i >= e) return;
    int s = src[i], d = dst[i];
    int pos = atomicAdd(&cursor[d], 1);
    es[pos] = make_int2(s, __float_as_int(dinv[s] * dinv[d]));
}

// ---------------- gather78: one wave per node, float2 x 40 lanes (stride 80) ----------------
__global__ __launch_bounds__(256) void k_gather78(const float* __restrict__ h,
    const int* __restrict__ rp, const int2* __restrict__ es,
    const float* __restrict__ dinv, float* __restrict__ agg) {
    int n = blockIdx.x * 4 + (threadIdx.x >> 6);
    int l = threadIdx.x & 63;
    if (l >= 40) return;
    float di = dinv[n], sw = di * di;
    float2 a = ((const float2*)(h + (size_t)n * 80))[l];
    a.x *= sw; a.y *= sw;
    int e = rp[n], e1 = rp[n + 1];
    int nf = (e1 - e) >> 3;
    if (nf > 0) {
        int2 cur[8];
#pragma unroll
        for (int j = 0; j < 8; j++) cur[j] = es[e + j];
        for (int b = 1; ; b++) {
            float2 v[8];
#pragma unroll
            for (int j = 0; j < 8; j++)
                v[j] = ((const float2*)(h + (size_t)cur[j].x * 80))[l];
            e += 8;
            bool more = (b < nf);
            int2 nxt[8];
            if (more) {
#pragma unroll
                for (int j = 0; j < 8; j++) nxt[j] = es[e + j];
            }
#pragma unroll
            for (int j = 0; j < 8; j++) {
                float w = __int_as_float(cur[j].y);
                a.x += v[j].x * w; a.y += v[j].y * w;
            }
            if (!more) break;
#pragma unroll
            for (int j = 0; j < 8; j++) cur[j] = nxt[j];
        }
    }
    for (; e < e1; e++) {
        int2 p = es[e];
        float w = __int_as_float(p.y);
        float2 v = ((const float2*)(h + (size_t)p.x * 80))[l];
        a.x += v.x * w; a.y += v.y * w;
    }
    *(float2*)&agg[(size_t)n * 80 + 2 * l] = a;
}

// ---------------- gather128: one wave per node, float2 x 64 lanes ----------------
__global__ __launch_bounds__(256) void k_gather128(const float* __restrict__ h,
    const int* __restrict__ rp, const int2* __restrict__ es,
    const float* __restrict__ dinv, float* __restrict__ agg) {
    int n = blockIdx.x * 4 + (threadIdx.x >> 6);
    int l = threadIdx.x & 63;
    float di = dinv[n], sw = di * di;
    float2 a = ((const float2*)(h + (size_t)n * 128))[l];
    a.x *= sw; a.y *= sw;
    int e = rp[n], e1 = rp[n + 1];
    int nf = (e1 - e) >> 3;
    if (nf > 0) {
        int2 cur[8];
#pragma unroll
        for (int j = 0; j < 8; j++) cur[j] = es[e + j];
        for (int b = 1; ; b++) {
            float2 v[8];
#pragma unroll
            for (int j = 0; j < 8; j++)
                v[j] = ((const float2*)(h + (size_t)cur[j].x * 128))[l];
            e += 8;
            bool more = (b < nf);
            int2 nxt[8];
            if (more) {
#pragma unroll
                for (int j = 0; j < 8; j++) nxt[j] = es[e + j];
            }
#pragma unroll
            for (int j = 0; j < 8; j++) {
                float w = __int_as_float(cur[j].y);
                a.x += v[j].x * w; a.y += v[j].y * w;
            }
            if (!more) break;
#pragma unroll
            for (int j = 0; j < 8; j++) cur[j] = nxt[j];
        }
    }
    for (; e < e1; e++) {
        int2 p = es[e];
        float w = __int_as_float(p.y);
        float2 v = ((const float2*)(h + (size_t)p.x * 128))[l];
        a.x += v.x * w; a.y += v.y * w;
    }
    ((float2*)(agg + (size_t)n * 128))[l] = a;
}

// ---------------- gemm1: h1 = relu(agg1[N,80-stride] @ W1[78,128] + b1) ----------------
// W1 fully LDS-resident; A via broadcast global loads (divergent-looking addr).
__global__ __launch_bounds__(256, 2) void k_gemm1(const float* __restrict__ A,
    const float* __restrict__ W, const float* __restrict__ bias,
    float* __restrict__ out) {
    __shared__ float Ws[80][128];   // 40 KB
    int tid = threadIdx.x;
    for (int i = tid; i < 80 * 128; i += 256) {
        int k = i >> 7, f = i & 127;
        Ws[k][f] = (k < 78) ? W[k * 128 + f] : 0.0f;
    }
    __syncthreads();
    int wv = tid >> 6, l = tid & 63;
    int task = blockIdx.x * 4 + wv;
    if (task >= NN / 16) return;    // 6250 tasks
    int n0 = task * 16;
    const float* a0p = A + (size_t)n0 * 80;
    int f0 = l * 2;
    float2 acc[16];
#pragma unroll
    for (int i = 0; i < 16; i++) acc[i] = make_float2(0.f, 0.f);

    for (int k = 0; k < 80; k += 4) {
        float2 w0 = *(const float2*)&Ws[k + 0][f0];
        float2 w1 = *(const float2*)&Ws[k + 1][f0];
        float2 w2 = *(const float2*)&Ws[k + 2][f0];
        float2 w3 = *(const float2*)&Ws[k + 3][f0];
#pragma unroll
        for (int i = 0; i < 16; i++) {
            float4 a = *(const float4*)(a0p + (size_t)i * 80 + k);
            acc[i].x += a.x * w0.x + a.y * w1.x + a.z * w2.x + a.w * w3.x;
            acc[i].y += a.x * w0.y + a.y * w1.y + a.z * w2.y + a.w * w3.y;
        }
    }
    float2 bv = *(const float2*)&bias[f0];
#pragma unroll
    for (int i = 0; i < 16; i++) {
        float2 o;
        o.x = fmaxf(acc[i].x + bv.x, 0.f);
        o.y = fmaxf(acc[i].y + bv.y, 0.f);
        *(float2*)&out[(size_t)(n0 + i) * 128 + f0] = o;
    }
}

// ---------------- gemm2+pool: relu(agg2[N,128] @ W2[128,256] + b2) -> segmax ----------------
// W double-buffered in 16-k LDS chunks; A double-buffered in registers
// (cur/nxt float4 x8, next kk-group's loads issued during current FMAs).
__global__ __launch_bounds__(256, 2) void k_gemm2_pool(const float* __restrict__ A,
    const float* __restrict__ W, const float* __restrict__ bias,
    const int* __restrict__ batch, unsigned* __restrict__ gmax) {
    __shared__ float Ws[2][16][256];   // 32 KB
    int tid = threadIdx.x;
    int wv = tid >> 6, l = tid & 63;
    int task = blockIdx.x * 4 + wv;    // 12500 tasks exact
    int n0 = task * 8;
    const float* a0p = A + (size_t)n0 * 128;
    int f0 = l * 4;
    float4 acc[8];
#pragma unroll
    for (int i = 0; i < 8; i++) acc[i] = make_float4(0.f, 0.f, 0.f, 0.f);

    // stage W chunk 0 and preload A group 0
    for (int i = tid; i < 1024; i += 256) {
        int k = i >> 6, f4 = (i & 63) << 2;
        *(float4*)&Ws[0][k][f4] = *(const float4*)&W[(size_t)k * 256 + f4];
    }
    float4 cur[8], nxt[8];
#pragma unroll
    for (int i = 0; i < 8; i++) cur[i] = *(const float4*)(a0p + (size_t)i * 128);
    __syncthreads();

    for (int c = 0; c < 8; c++) {
        int buf = c & 1;
        if (c < 7) {
            int k0n = (c + 1) * 16;
            for (int i = tid; i < 1024; i += 256) {
                int k = i >> 6, f4 = (i & 63) << 2;
                *(float4*)&Ws[1 - buf][k][f4] = *(const float4*)&W[(size_t)(k0n + k) * 256 + f4];
            }
        }
#pragma unroll
        for (int g = 0; g < 4; g++) {
            int kk = g * 4;
            int kn = c * 16 + kk + 4;
            if (kn < 128) {
#pragma unroll
                for (int i = 0; i < 8; i++)
                    nxt[i] = *(const float4*)(a0p + (size_t)i * 128 + kn);
            }
            float4 w0 = *(const float4*)&Ws[buf][kk + 0][f0];
            float4 w1 = *(const float4*)&Ws[buf][kk + 1][f0];
            float4 w2 = *(const float4*)&Ws[buf][kk + 2][f0];
            float4 w3 = *(const float4*)&Ws[buf][kk + 3][f0];
#pragma unroll
            for (int i = 0; i < 8; i++) {
                acc[i].x += cur[i].x * w0.x + cur[i].y * w1.x + cur[i].z * w2.x + cur[i].w * w3.x;
                acc[i].y += cur[i].x * w0.y + cur[i].y * w1.y + cur[i].z * w2.y + cur[i].w * w3.y;
                acc[i].z += cur[i].x * w0.z + cur[i].y * w1.z + cur[i].z * w2.z + cur[i].w * w3.z;
                acc[i].w += cur[i].x * w0.w + cur[i].y * w1.w + cur[i].z * w2.w + cur[i].w * w3.w;
            }
#pragma unroll
            for (int i = 0; i < 8; i++) cur[i] = nxt[i];
        }
        __syncthreads();
    }

    // epilogue: bias + relu + flush-on-change segment max (batch sorted)
    float4 bv = *(const float4*)&bias[f0];
    int curg = -1;
    float4 m = make_float4(0.f, 0.f, 0.f, 0.f);
#pragma unroll
    for (int i = 0; i < 8; i++) {
        int g = batch[n0 + i];
        float4 v;
        v.x = fmaxf(acc[i].x + bv.x, 0.f); v.y = fmaxf(acc[i].y + bv.y, 0.f);
        v.z = fmaxf(acc[i].z + bv.z, 0.f); v.w = fmaxf(acc[i].w + bv.w, 0.f);
        if (g != curg) {
            if (curg >= 0) {
                unsigned* gp = &gmax[(size_t)curg * 256 + f0];
                atomicMax(&gp[0], __float_as_uint(m.x));
                atomicMax(&gp[1], __float_as_uint(m.y));
                atomicMax(&gp[2], __float_as_uint(m.z));
                atomicMax(&gp[3], __float_as_uint(m.w));
            }
            curg = g; m = v;
        } else {
            m.x = fmaxf(m.x, v.x); m.y = fmaxf(m.y, v.y);
            m.z = fmaxf(m.z, v.z); m.w = fmaxf(m.w, v.w);
        }
    }
    if (curg >= 0) {
        unsigned* gp = &gmax[(size_t)curg * 256 + f0];
        atomicMax(&gp[0], __float_as_uint(m.x));
        atomicMax(&gp[1], __float_as_uint(m.y));
        atomicMax(&gp[2], __float_as_uint(m.z));
        atomicMax(&gp[3], __float_as_uint(m.w));
    }
}

// ---------------- fused MLP head: out = (relu(g@Wg1+bg1)) @ Wg2 + bg2 ----------------
__global__ __launch_bounds__(256) void k_gemm34(const float* __restrict__ A,
    const float* __restrict__ Wg1, const float* __restrict__ bg1,
    const float* __restrict__ Wg2, const float* __restrict__ bg2,
    float* __restrict__ out) {
    __shared__ float rs[256];
    __shared__ float g1s[1024];
    __shared__ float part[128];
    int g = blockIdx.x, tid = threadIdx.x;
    rs[tid] = A[g * 256 + tid];
    __syncthreads();
    float acc[4] = {0.f, 0.f, 0.f, 0.f};
    for (int k = 0; k < 256; k++) {
        float a = rs[k];
#pragma unroll
        for (int j = 0; j < 4; j++) acc[j] += a * Wg1[k * 1024 + tid + j * 256];
    }
#pragma unroll
    for (int j = 0; j < 4; j++) {
        int f = tid + j * 256;
        g1s[f] = fmaxf(acc[j] + bg1[f], 0.0f);
    }
    __syncthreads();
    int f = tid & 127, h = tid >> 7;
    float s = 0.0f;
    int kbase = h * 512;
    for (int k = 0; k < 512; k++) s += g1s[kbase + k] * Wg2[(size_t)(kbase + k) * 128 + f];
    if (h == 0) part[f] = s;
    __syncthreads();
    if (h == 1) out[g * 128 + f] = s + part[f] + bg2[f];
}

extern "C" void kernel_launch(void* const* d_in, const int* in_sizes, int n_in,
                              void* d_out, int out_size, void* d_ws, size_t ws_size,
                              hipStream_t stream) {
    const float* x    = (const float*)d_in[0];
    const int*   ei   = (const int*)d_in[1];
    const int*   batch= (const int*)d_in[2];
    const float* W1   = (const float*)d_in[3];
    const float* b1   = (const float*)d_in[4];
    const float* W2   = (const float*)d_in[5];
    const float* b2   = (const float*)d_in[6];
    const float* Wg1  = (const float*)d_in[7];
    const float* bg1  = (const float*)d_in[8];
    const float* Wg2  = (const float*)d_in[9];
    const float* bg2  = (const float*)d_in[10];
    const int* src = ei;
    const int* dst = ei + NE;

    char* w8 = (char*)d_ws;
    int*   cnt     = (int*)w8;                 w8 += (size_t)NN * 4;
    int*   row_ptr = (int*)w8;                 w8 += (size_t)(NN + 4) * 4;
    int*   cursor  = (int*)w8;                 w8 += (size_t)NN * 4;
    int*   bsum    = (int*)w8;                 w8 += 128 * 4;
    int2*  es      = (int2*)w8;                w8 += (size_t)NE * 8;
    float* dinv    = (float*)w8;               w8 += (size_t)NN * 4;
    float* agg1    = (float*)w8;               w8 += (size_t)NN * 80 * 4;   // stride 80
    float* h1      = (float*)w8;               w8 += (size_t)NN * 128 * 4;
    float* agg2    = (float*)w8;               w8 += (size_t)NN * 128 * 4;  // also xp overlay
    unsigned* gmax = (unsigned*)w8;            w8 += (size_t)NG * 256 * 4;
    float* xp      = (float*)agg2;   // xp lifetime: xpad..gather78; agg2 starts at gather128

    // CSR build
    k_zero_int<<<(NN + 255) / 256, 256, 0, stream>>>(cnt, NN);
    k_xpad<<<(NN * 80 + 255) / 256, 256, 0, stream>>>(x, xp);
    k_hist<<<(NE + 255) / 256, 256, 0, stream>>>(dst, cnt, NE);
    k_bsum<<<NBLK, 256, 0, stream>>>(cnt, bsum);
    k_scan_blocks<<<NBLK, 256, 0, stream>>>(cnt, bsum, row_ptr, cursor, dinv);
    k_fillslots<<<(NE + 255) / 256, 256, 0, stream>>>(src, dst, dinv, cursor, es, (float*)gmax, NE);

    // layer 1
    k_gather78<<<NN / 4, 256, 0, stream>>>(xp, row_ptr, es, dinv, agg1);
    k_gemm1<<<(NN / 16 + 3) / 4, 256, 0, stream>>>(agg1, W1, b1, h1);

    // layer 2
    k_gather128<<<NN / 4, 256, 0, stream>>>(h1, row_ptr, es, dinv, agg2);
    k_gemm2_pool<<<NN / 32, 256, 0, stream>>>(agg2, W2, b2, batch, gmax);

    // fused MLP head
    k_gemm34<<<NG, 256, 0, stream>>>((const float*)gmax, Wg1, bg1, Wg2, bg2, (float*)d_out);
}

// Round 9
// 750.260 us; speedup vs baseline: 1.1953x; 1.1953x over previous
//
#include <hip/hip_runtime.h>
#include <hip/hip_bf16.h>

// GCN forward, CSR-gather formulation.
// Gathers: fabric-bound (~3.85 TB/s random-granule ceiling, r6). Pipelined 8-deep.
// GEMMs: W staged in LDS (single buffer); A via readfirstlane-uniform s_load into
//   SGPRs (zero VGPR cost; 1 SGPR operand per v_fma is legal). NO min-waves
//   launch bound (r7: =4 starved VGPRs; r8: =2 collapsed occupancy + spilled).
// gemm2: 16 nodes/wave (512 FMA-cyc per k-group amortizes s_load/ds_read waits).

#define NN 100000
#define NE 1600000
#define NG 512
#define NBLK ((NN + 1023) / 1024)   // 98 scan blocks

// ---------------- CSR build (counting sort by dst) ----------------

__global__ void k_zero_int(int* p, int n) {
    int i = blockIdx.x * blockDim.x + threadIdx.x;
    if (i < n) p[i] = 0;
}

__global__ void k_hist(const int* __restrict__ dst, int* cnt, int e) {
    int i = blockIdx.x * blockDim.x + threadIdx.x;
    if (i < e) atomicAdd(&cnt[dst[i]], 1);
}

// pad x[N,78] -> xp[N,80] (320B rows, 3-line span)
__global__ void k_xpad(const float* __restrict__ x, float* __restrict__ xp) {
    int i = blockIdx.x * blockDim.x + threadIdx.x;   // over NN*80
    if (i >= NN * 80) return;
    int n = i / 80, c = i - n * 80;
    xp[i] = (c < 78) ? x[(size_t)n * 78 + c] : 0.0f;
}

__global__ __launch_bounds__(256) void k_bsum(const int* __restrict__ cnt, int* __restrict__ bsum) {
    __shared__ int s[256];
    int b = blockIdx.x, t = threadIdx.x;
    int base = b * 1024 + t * 4;
    int v = 0;
#pragma unroll
    for (int j = 0; j < 4; j++) { int i = base + j; if (i < NN) v += cnt[i]; }
    s[t] = v; __syncthreads();
    for (int off = 128; off > 0; off >>= 1) {
        if (t < off) s[t] += s[t + off];
        __syncthreads();
    }
    if (t == 0) bsum[b] = s[0];
}

// per-block scan (+ inlined 98-entry bsum scan) -> row_ptr, cursor; also dinv.
__global__ __launch_bounds__(256) void k_scan_blocks(const int* __restrict__ cnt,
    const int* __restrict__ bsum, int* __restrict__ row_ptr, int* __restrict__ cursor,
    float* __restrict__ dinv) {
    __shared__ int s[256];
    __shared__ int sb[128];
    int b = blockIdx.x, t = threadIdx.x;
    if (t < 128) sb[t] = (t < NBLK) ? bsum[t] : 0;
    __syncthreads();
    if (t < 128) {
        for (int off = 1; off < 128; off <<= 1) {
            int u = (t >= off) ? sb[t - off] : 0;
            __syncthreads();
            sb[t] += u;
            __syncthreads();
        }
    } else {
        for (int off = 1; off < 128; off <<= 1) { __syncthreads(); __syncthreads(); }
    }
    __syncthreads();
    int boff = (b == 0) ? 0 : sb[b - 1];

    int base = b * 1024 + t * 4;
    int v[4]; int sum = 0;
#pragma unroll
    for (int j = 0; j < 4; j++) {
        int i = base + j;
        v[j] = (i < NN) ? cnt[i] : 0;
        sum += v[j];
        if (i < NN) dinv[i] = rsqrtf((float)v[j] + 1.0f);
    }
    s[t] = sum; __syncthreads();
    for (int off = 1; off < 256; off <<= 1) {
        int u = (t >= off) ? s[t - off] : 0;
        __syncthreads();
        s[t] += u;
        __syncthreads();
    }
    int excl = s[t] - sum + boff;
#pragma unroll
    for (int j = 0; j < 4; j++) {
        int i = base + j;
        if (i < NN) { row_ptr[i] = excl; cursor[i] = excl; excl += v[j]; }
    }
    if (b == 0 && t == 0) row_ptr[NN] = NE;
}

// counting-sort fill (one packed 8B store per edge) + gmax zero-init
__global__ void k_fillslots(const int* __restrict__ src, const int* __restrict__ dst,
    const float* __restrict__ dinv, int* cursor, int2* __restrict__ es,
    float* __restrict__ gmax, int e) {
    int i = blockIdx.x * blockDim.x + threadIdx.x;
    if (i < NG * 256) gmax[i] = 0.0f;
    if (i >= e) return;
    int s = src[i], d = dst[i];
    int pos = atomicAdd(&cursor[d], 1);
    es[pos] = make_int2(s, __float_as_int(dinv[s] * dinv[d]));
}

// ---------------- gather78: one wave per node, float2 x 40 lanes (stride 80) ----------------
__global__ __launch_bounds__(256) void k_gather78(const float* __restrict__ h,
    const int* __restrict__ rp, const int2* __restrict__ es,
    const float* __restrict__ dinv, float* __restrict__ agg) {
    int n = blockIdx.x * 4 + (threadIdx.x >> 6);
    int l = threadIdx.x & 63;
    if (l >= 40) return;
    float di = dinv[n], sw = di * di;
    float2 a = ((const float2*)(h + (size_t)n * 80))[l];
    a.x *= sw; a.y *= sw;
    int e = rp[n], e1 = rp[n + 1];
    int nf = (e1 - e) >> 3;
    if (nf > 0) {
        int2 cur[8];
#pragma unroll
        for (int j = 0; j < 8; j++) cur[j] = es[e + j];
        for (int b = 1; ; b++) {
            float2 v[8];
#pragma unroll
            for (int j = 0; j < 8; j++)
                v[j] = ((const float2*)(h + (size_t)cur[j].x * 80))[l];
            e += 8;
            bool more = (b < nf);
            int2 nxt[8];
            if (more) {
#pragma unroll
                for (int j = 0; j < 8; j++) nxt[j] = es[e + j];
            }
#pragma unroll
            for (int j = 0; j < 8; j++) {
                float w = __int_as_float(cur[j].y);
                a.x += v[j].x * w; a.y += v[j].y * w;
            }
            if (!more) break;
#pragma unroll
            for (int j = 0; j < 8; j++) cur[j] = nxt[j];
        }
    }
    for (; e < e1; e++) {
        int2 p = es[e];
        float w = __int_as_float(p.y);
        float2 v = ((const float2*)(h + (size_t)p.x * 80))[l];
        a.x += v.x * w; a.y += v.y * w;
    }
    *(float2*)&agg[(size_t)n * 80 + 2 * l] = a;
}

// ---------------- gather128: one wave per node, float2 x 64 lanes ----------------
__global__ __launch_bounds__(256) void k_gather128(const float* __restrict__ h,
    const int* __restrict__ rp, const int2* __restrict__ es,
    const float* __restrict__ dinv, float* __restrict__ agg) {
    int n = blockIdx.x * 4 + (threadIdx.x >> 6);
    int l = threadIdx.x & 63;
    float di = dinv[n], sw = di * di;
    float2 a = ((const float2*)(h + (size_t)n * 128))[l];
    a.x *= sw; a.y *= sw;
    int e = rp[n], e1 = rp[n + 1];
    int nf = (e1 - e) >> 3;
    if (nf > 0) {
        int2 cur[8];
#pragma unroll
        for (int j = 0; j < 8; j++) cur[j] = es[e + j];
        for (int b = 1; ; b++) {
            float2 v[8];
#pragma unroll
            for (int j = 0; j < 8; j++)
                v[j] = ((const float2*)(h + (size_t)cur[j].x * 128))[l];
            e += 8;
            bool more = (b < nf);
            int2 nxt[8];
            if (more) {
#pragma unroll
                for (int j = 0; j < 8; j++) nxt[j] = es[e + j];
            }
#pragma unroll
            for (int j = 0; j < 8; j++) {
                float w = __int_as_float(cur[j].y);
                a.x += v[j].x * w; a.y += v[j].y * w;
            }
            if (!more) break;
#pragma unroll
            for (int j = 0; j < 8; j++) cur[j] = nxt[j];
        }
    }
    for (; e < e1; e++) {
        int2 p = es[e];
        float w = __int_as_float(p.y);
        float2 v = ((const float2*)(h + (size_t)p.x * 128))[l];
        a.x += v.x * w; a.y += v.y * w;
    }
    ((float2*)(agg + (size_t)n * 128))[l] = a;
}

// ---------------- gemm1: h1 = relu(agg1[N,80-stride] @ W1[78,128] + b1) ----------------
// W1 fully LDS-resident; A via readfirstlane-uniform s_load (SGPR operand).
__global__ __launch_bounds__(256) void k_gemm1(const float* __restrict__ A,
    const float* __restrict__ W, const float* __restrict__ bias,
    float* __restrict__ out) {
    __shared__ float Ws[80][128];   // 40 KB
    int tid = threadIdx.x;
    for (int i = tid; i < 80 * 128; i += 256) {
        int k = i >> 7, f = i & 127;
        Ws[k][f] = (k < 78) ? W[k * 128 + f] : 0.0f;
    }
    __syncthreads();
    int wv = tid >> 6, l = tid & 63;
    int task = blockIdx.x * 4 + wv;
    if (task >= NN / 16) return;    // 6250 tasks; no barriers after this point
    task = __builtin_amdgcn_readfirstlane(task);
    int n0 = task * 16;
    const float* a0p = A + (size_t)n0 * 80;
    int f0 = l * 2;
    float2 acc[16];
#pragma unroll
    for (int i = 0; i < 16; i++) acc[i] = make_float2(0.f, 0.f);

    for (int k = 0; k < 80; k += 4) {
        float2 w0 = *(const float2*)&Ws[k + 0][f0];
        float2 w1 = *(const float2*)&Ws[k + 1][f0];
        float2 w2 = *(const float2*)&Ws[k + 2][f0];
        float2 w3 = *(const float2*)&Ws[k + 3][f0];
#pragma unroll
        for (int i = 0; i < 16; i++) {
            float4 a = *(const float4*)(a0p + (size_t)i * 80 + k);
            acc[i].x += a.x * w0.x + a.y * w1.x + a.z * w2.x + a.w * w3.x;
            acc[i].y += a.x * w0.y + a.y * w1.y + a.z * w2.y + a.w * w3.y;
        }
    }
    float2 bv = *(const float2*)&bias[f0];
#pragma unroll
    for (int i = 0; i < 16; i++) {
        float2 o;
        o.x = fmaxf(acc[i].x + bv.x, 0.f);
        o.y = fmaxf(acc[i].y + bv.y, 0.f);
        *(float2*)&out[(size_t)(n0 + i) * 128 + f0] = o;
    }
}

// ---------------- gemm2+pool: relu(agg2[N,128] @ W2[128,256] + b2) -> segmax ----------------
// 16 nodes/wave (acc 64 VGPR); W2 in single-buffered 16-k LDS chunks; A via
// readfirstlane-uniform s_load. Last block's spare wave clamps to task 6249
// (duplicate compute; atomicMax epilogue is idempotent).
__global__ __launch_bounds__(256) void k_gemm2_pool(const float* __restrict__ A,
    const float* __restrict__ W, const float* __restrict__ bias,
    const int* __restrict__ batch, unsigned* __restrict__ gmax) {
    __shared__ float Ws[16][256];   // 16 KB
    int tid = threadIdx.x;
    int wv = tid >> 6, l = tid & 63;
    int task = blockIdx.x * 4 + wv;
    if (task > NN / 16 - 1) task = NN / 16 - 1;   // clamp keeps all waves in barriers
    task = __builtin_amdgcn_readfirstlane(task);
    int n0 = task * 16;
    const float* a0p = A + (size_t)n0 * 128;
    int f0 = l * 4;
    float4 acc[16];
#pragma unroll
    for (int i = 0; i < 16; i++) acc[i] = make_float4(0.f, 0.f, 0.f, 0.f);

    for (int c = 0; c < 8; c++) {
        int k0 = c * 16;
        __syncthreads();
        for (int i = tid; i < 1024; i += 256) {   // 16x256 floats as float4
            int k = i >> 6, f4 = (i & 63) << 2;
            *(float4*)&Ws[k][f4] = *(const float4*)&W[(size_t)(k0 + k) * 256 + f4];
        }
        __syncthreads();
#pragma unroll
        for (int kk = 0; kk < 16; kk += 4) {
            float4 w0 = *(const float4*)&Ws[kk + 0][f0];
            float4 w1 = *(const float4*)&Ws[kk + 1][f0];
            float4 w2 = *(const float4*)&Ws[kk + 2][f0];
            float4 w3 = *(const float4*)&Ws[kk + 3][f0];
#pragma unroll
            for (int i = 0; i < 16; i++) {
                float4 a = *(const float4*)(a0p + (size_t)i * 128 + k0 + kk);
                acc[i].x += a.x * w0.x + a.y * w1.x + a.z * w2.x + a.w * w3.x;
                acc[i].y += a.x * w0.y + a.y * w1.y + a.z * w2.y + a.w * w3.y;
                acc[i].z += a.x * w0.z + a.y * w1.z + a.z * w2.z + a.w * w3.z;
                acc[i].w += a.x * w0.w + a.y * w1.w + a.z * w2.w + a.w * w3.w;
            }
        }
    }

    // epilogue: bias + relu + flush-on-change segment max (batch sorted)
    float4 bv = *(const float4*)&bias[f0];
    int curg = -1;
    float4 m = make_float4(0.f, 0.f, 0.f, 0.f);
#pragma unroll
    for (int i = 0; i < 16; i++) {
        int g = batch[n0 + i];
        float4 v;
        v.x = fmaxf(acc[i].x + bv.x, 0.f); v.y = fmaxf(acc[i].y + bv.y, 0.f);
        v.z = fmaxf(acc[i].z + bv.z, 0.f); v.w = fmaxf(acc[i].w + bv.w, 0.f);
        if (g != curg) {
            if (curg >= 0) {
                unsigned* gp = &gmax[(size_t)curg * 256 + f0];
                atomicMax(&gp[0], __float_as_uint(m.x));
                atomicMax(&gp[1], __float_as_uint(m.y));
                atomicMax(&gp[2], __float_as_uint(m.z));
                atomicMax(&gp[3], __float_as_uint(m.w));
            }
            curg = g; m = v;
        } else {
            m.x = fmaxf(m.x, v.x); m.y = fmaxf(m.y, v.y);
            m.z = fmaxf(m.z, v.z); m.w = fmaxf(m.w, v.w);
        }
    }
    if (curg >= 0) {
        unsigned* gp = &gmax[(size_t)curg * 256 + f0];
        atomicMax(&gp[0], __float_as_uint(m.x));
        atomicMax(&gp[1], __float_as_uint(m.y));
        atomicMax(&gp[2], __float_as_uint(m.z));
        atomicMax(&gp[3], __float_as_uint(m.w));
    }
}

// ---------------- fused MLP head: out = (relu(g@Wg1+bg1)) @ Wg2 + bg2 ----------------
__global__ __launch_bounds__(256) void k_gemm34(const float* __restrict__ A,
    const float* __restrict__ Wg1, const float* __restrict__ bg1,
    const float* __restrict__ Wg2, const float* __restrict__ bg2,
    float* __restrict__ out) {
    __shared__ float rs[256];
    __shared__ float g1s[1024];
    __shared__ float part[128];
    int g = blockIdx.x, tid = threadIdx.x;
    rs[tid] = A[g * 256 + tid];
    __syncthreads();
    float acc[4] = {0.f, 0.f, 0.f, 0.f};
    for (int k = 0; k < 256; k++) {
        float a = rs[k];
#pragma unroll
        for (int j = 0; j < 4; j++) acc[j] += a * Wg1[k * 1024 + tid + j * 256];
    }
#pragma unroll
    for (int j = 0; j < 4; j++) {
        int f = tid + j * 256;
        g1s[f] = fmaxf(acc[j] + bg1[f], 0.0f);
    }
    __syncthreads();
    int f = tid & 127, h = tid >> 7;
    float s = 0.0f;
    int kbase = h * 512;
    for (int k = 0; k < 512; k++) s += g1s[kbase + k] * Wg2[(size_t)(kbase + k) * 128 + f];
    if (h == 0) part[f] = s;
    __syncthreads();
    if (h == 1) out[g * 128 + f] = s + part[f] + bg2[f];
}

extern "C" void kernel_launch(void* const* d_in, const int* in_sizes, int n_in,
                              void* d_out, int out_size, void* d_ws, size_t ws_size,
                              hipStream_t stream) {
    const float* x    = (const float*)d_in[0];
    const int*   ei   = (const int*)d_in[1];
    const int*   batch= (const int*)d_in[2];
    const float* W1   = (const float*)d_in[3];
    const float* b1   = (const float*)d_in[4];
    const float* W2   = (const float*)d_in[5];
    const float* b2   = (const float*)d_in[6];
    const float* Wg1  = (const float*)d_in[7];
    const float* bg1  = (const float*)d_in[8];
    const float* Wg2  = (const float*)d_in[9];
    const float* bg2  = (const float*)d_in[10];
    const int* src = ei;
    const int* dst = ei + NE;

    char* w8 = (char*)d_ws;
    int*   cnt     = (int*)w8;                 w8 += (size_t)NN * 4;
    int*   row_ptr = (int*)w8;                 w8 += (size_t)(NN + 4) * 4;
    int*   cursor  = (int*)w8;                 w8 += (size_t)NN * 4;
    int*   bsum    = (int*)w8;                 w8 += 128 * 4;
    int2*  es      = (int2*)w8;                w8 += (size_t)NE * 8;
    float* dinv    = (float*)w8;               w8 += (size_t)NN * 4;
    float* agg1    = (float*)w8;               w8 += (size_t)NN * 80 * 4;   // stride 80
    float* h1      = (float*)w8;               w8 += (size_t)NN * 128 * 4;
    float* agg2    = (float*)w8;               w8 += (size_t)NN * 128 * 4;  // also xp overlay
    unsigned* gmax = (unsigned*)w8;            w8 += (size_t)NG * 256 * 4;
    float* xp      = (float*)agg2;   // xp lifetime: xpad..gather78; agg2 starts at gather128

    // CSR build
    k_zero_int<<<(NN + 255) / 256, 256, 0, stream>>>(cnt, NN);
    k_xpad<<<(NN * 80 + 255) / 256, 256, 0, stream>>>(x, xp);
    k_hist<<<(NE + 255) / 256, 256, 0, stream>>>(dst, cnt, NE);
    k_bsum<<<NBLK, 256, 0, stream>>>(cnt, bsum);
    k_scan_blocks<<<NBLK, 256, 0, stream>>>(cnt, bsum, row_ptr, cursor, dinv);
    k_fillslots<<<(NE + 255) / 256, 256, 0, stream>>>(src, dst, dinv, cursor, es, (float*)gmax, NE);

    // layer 1
    k_gather78<<<NN / 4, 256, 0, stream>>>(xp, row_ptr, es, dinv, agg1);
    k_gemm1<<<(NN / 16 + 3) / 4, 256, 0, stream>>>(agg1, W1, b1, h1);

    // layer 2
    k_gather128<<<NN / 4, 256, 0, stream>>>(h1, row_ptr, es, dinv, agg2);
    k_gemm2_pool<<<(NN / 16 + 3) / 4, 256, 0, stream>>>(agg2, W2, b2, batch, gmax);

    // fused MLP head
    k_gemm34<<<NG, 256, 0, stream>>>((const float*)gmax, Wg1, bg1, Wg2, bg2, (float*)d_out);
}